// Round 5
// baseline (10898.349 us; speedup 1.0000x reference)
//
#include <hip/hip_runtime.h>
#include <stdint.h>

// BiLSTM-CRF on gfx950 — fp32 (validated absmax 0.0). R11: abandon the VGPR
// residency fight (R7/R9/R10: allocator pins 1024-thr WGs at 64 VGPR and
// spills). Instead share the Whh stream ACROSS batches: each WG = (batch-pair,
// dir, hidden-chunk of 64 units): 256 WGs x 512 thr, streams only 256 KB/step
// (vs 1 MB) against the measured ~135 GB/s per-CU L2 wall. h exchanged per
// step among the 4 chunk-WGs of a (bpair,dir) group via parity-double-buffered
// global H + device-scope release counter (leader-spin + barrier). Per-thread
// FP sequence identical to R8 -> bitwise-same h.

#define T_ 256
#define B_ 64
#define EPAD 304
#define KTAG 20
#define TB_ (T_ * B_)

__device__ __forceinline__ float rlane(float v, int l) {
  return __int_as_float(__builtin_amdgcn_readlane(__float_as_int(v), l));
}

// ---------------- prep ----------------

__global__ void prep_embed(const int* __restrict__ x, const float* __restrict__ emb,
                           float* __restrict__ xsA) {
  int r = blockIdx.x;
  int tok = x[r];
  const float* src = emb + (size_t)tok * 300;
  for (int e = threadIdx.x; e < EPAD; e += 64)
    xsA[(size_t)r * EPAD + e] = (e < 300) ? src[e] : 0.f;
}

// B0t[2048][304]: Wih0 [2*1024,300] K-padded to 304.
__global__ void prep_b0t(const float* __restrict__ Wih0, float* __restrict__ B0t) {
  int idx = blockIdx.x * 256 + threadIdx.x;
  if (idx >= 2048 * EPAD) return;
  int n = idx / EPAD, k = idx % EPAD;
  B0t[idx] = (k < 300) ? Wih0[(size_t)n * 300 + k] : 0.f;
}

// Bot[64][512]: W_out [20,512] rows padded to 64; biaso[64] likewise.
__global__ void prep_bot64(const float* __restrict__ Wout, float* __restrict__ Bot,
                           const float* __restrict__ bout, float* __restrict__ biaso) {
  int idx = blockIdx.x * 256 + threadIdx.x;   // 64*512
  int n = idx >> 9, k = idx & 511;
  Bot[idx] = (n < KTAG) ? Wout[(size_t)n * 512 + k] : 0.f;
  if (idx < 64) biaso[idx] = (idx < KTAG) ? bout[idx] : 0.f;
}

// Whh [2][1024 rows][256 k] -> whhS[d][chunk][q=k/4][rr][e]: chunk = unit>>6,
// rr = (unit&63)*4 + gate. Lane (wq,l) of the lstm kernel reads rr = wq*64+l,
// so a wave's 64 lanes read 1 KB contiguous; twin waves (b0/b1) dedup in L1.
__global__ void prep_whh3(const float* __restrict__ Whh, float* __restrict__ whhS) {
  int idx = blockIdx.x * 256 + threadIdx.x;   // 524288 = 2*1024*256
  int d = idx >> 18, rem = idx & 262143, row = rem >> 8, k = rem & 255;
  float v = Whh[(size_t)d * 262144 + (size_t)row * 256 + k];
  int gt = row >> 8, u = row & 255;
  int chunk = u >> 6, j = u & 63;
  int rr = j * 4 + gt;
  int q = k >> 2, e = k & 3;
  whhS[((((size_t)d * 4 + chunk) * 64 + q) * 256 + rr) * 4 + e] = v;
}

// zero the parity-0 H plane (h_0 = 0) and the 64 group counters
__global__ void zero_sync(float* __restrict__ Hg, int* __restrict__ ctr) {
  int i = blockIdx.x * 256 + threadIdx.x;
  if (i < 32768) Hg[i] = 0.f;
  else if (i < 32768 + 64) ctr[i - 32768] = 0;
}

// ---------------- fp32 GEMM: C[M,N] = A[M,K] * Bt[N,K]^T + bias ----------------
__global__ __launch_bounds__(256) void gemm_f32(
    const float* __restrict__ A, int lda, const float* __restrict__ Bt, int ldb,
    float* __restrict__ C, int ldc, const float* __restrict__ bias,
    int ntn, int K) {
  const int tm = blockIdx.x / ntn, tn = blockIdx.x % ntn;
  const int m0 = tm * 64, n0 = tn * 64;
  __shared__ __align__(16) float As[16][64];
  __shared__ __align__(16) float Bs[16][64];
  const int tid = threadIdx.x;
  const int mm = tid >> 2, kq = (tid & 3) * 4;
  const int tx = tid & 15, ty = tid >> 4;
  float acc[4][4] = {};
  for (int k0 = 0; k0 < K; k0 += 16) {
    float4 av = *(const float4*)&A[(size_t)(m0 + mm) * lda + k0 + kq];
    float4 bv = *(const float4*)&Bt[(size_t)(n0 + mm) * ldb + k0 + kq];
    __syncthreads();                       // guard prev-iter LDS reads
    As[kq + 0][mm] = av.x; As[kq + 1][mm] = av.y;
    As[kq + 2][mm] = av.z; As[kq + 3][mm] = av.w;
    Bs[kq + 0][mm] = bv.x; Bs[kq + 1][mm] = bv.y;
    Bs[kq + 2][mm] = bv.z; Bs[kq + 3][mm] = bv.w;
    __syncthreads();
#pragma unroll
    for (int kk = 0; kk < 16; ++kk) {
      float4 a4 = *(const float4*)&As[kk][ty * 4];
      float4 b4 = *(const float4*)&Bs[kk][tx * 4];
      acc[0][0] += a4.x * b4.x; acc[0][1] += a4.x * b4.y;
      acc[0][2] += a4.x * b4.z; acc[0][3] += a4.x * b4.w;
      acc[1][0] += a4.y * b4.x; acc[1][1] += a4.y * b4.y;
      acc[1][2] += a4.y * b4.z; acc[1][3] += a4.y * b4.w;
      acc[2][0] += a4.z * b4.x; acc[2][1] += a4.z * b4.y;
      acc[2][2] += a4.z * b4.z; acc[2][3] += a4.z * b4.w;
      acc[3][0] += a4.w * b4.x; acc[3][1] += a4.w * b4.y;
      acc[3][2] += a4.w * b4.z; acc[3][3] += a4.w * b4.w;
    }
  }
#pragma unroll
  for (int i = 0; i < 4; ++i)
#pragma unroll
    for (int j = 0; j < 4; ++j)
      C[(size_t)(m0 + ty * 4 + i) * ldc + n0 + tx * 4 + j] =
          acc[i][j] + bias[n0 + tx * 4 + j];
}

// ---------------- persistent LSTM recurrence (fp32, batch-shared Whh) ---------
// blk = bp*8 + d*4 + chunk. WG: 512 thr = 8 waves; wave wv: b = bp*2 + (wv>>2),
// rr = (wv&3)*64 + lane. Thread owns gate-row gt=rr&3 of unit chunk*64+(rr>>2)
// for ONE b; streams w[rr] (256 KB unique/WG/step, b0/b1 twins dedup in L1).
// h: global parity buffer Hg[par][d][b][256]; lane reads h[4l..4l+3], rlane
// broadcast (identical FP sequence to R8). Group (bp,d) = 4 chunk-WGs sync per
// step via release-counter; leader spins (capped), barrier distributes.
__global__ __launch_bounds__(512) void lstm_rec(
    const float* __restrict__ xg, const float* __restrict__ whhS,
    float* __restrict__ out, const int* __restrict__ lens,
    float* __restrict__ Hg, int* __restrict__ ctr, int* __restrict__ diagf) {
  __shared__ float occupad[20496];   // 82 KB: forces 1 WG/CU (grid=256=#CUs)
  const int blk = blockIdx.x;
  const int chunk = blk & 3, d = (blk >> 2) & 1, bp = blk >> 3;
  const int tg = threadIdx.x;
  const int wv_ = tg >> 6, l = tg & 63;
  const int b_i = wv_ >> 2, wq = wv_ & 3;
  const int b = bp * 2 + b_i;
  const int rr = (wq << 6) | l;
  const int gt = rr & 3, j = rr >> 2;
  const int unit = chunk * 64 + j;
  const int row = gt * 256 + unit;
  const int len = lens[b];
  const int maxlen = lens[bp * 2];           // lens sorted descending
  if (len == 0x7fffffff) occupad[0] = (float)tg;  // never true; keeps LDS alive
  const float* wbase = whhS + ((size_t)(d * 4 + chunk) << 16);  // [q][rr][4]
  int* myc = ctr + (d * 32 + bp);
  const int qb = l & ~3;
  float c = 0.f;
  long polls = 0;

  for (int s = 0; s < maxlen; ++s) {
    if (tg == 0) {                           // wait: h_s published by all 4 WGs
      const int tgt = 4 * s;
      while (__hip_atomic_load(myc, __ATOMIC_ACQUIRE, __HIP_MEMORY_SCOPE_AGENT) < tgt) {
        __builtin_amdgcn_s_sleep(2);
        if (++polls > 20000000L) { atomicOr(diagf, 2); break; }
      }
    }
    __syncthreads();                         // release whole WG; L1 already inv'd
    const float* hsrc = Hg + (((size_t)(s & 1) * 2 + d) * 64 + b) * 256;
    float* hdst = Hg + (((size_t)((s + 1) & 1) * 2 + d) * 64 + b) * 256;
    if (s < len) {
      const int t = d ? (len - 1 - s) : s;   // bwd consumes & writes reversed pos
      const float xv = xg[(size_t)(t * B_ + b) * 2048 + d * 1024 + row];
      float4 hv = *(const float4*)&hsrc[l * 4];   // lane l: h[4l..4l+3]
      float acc0 = 0.f, acc1 = 0.f;
#pragma unroll 8
      for (int q = 0; q < 64; ++q) {         // k ascending, same FP order as R8
        float4 wvq = *(const float4*)(wbase + (((size_t)q << 8) + rr) * 4);
        float b0 = rlane(hv.x, q), b1 = rlane(hv.y, q);
        float b2 = rlane(hv.z, q), b3 = rlane(hv.w, q);
        acc0 += wvq.x * b0 + wvq.y * b1;
        acc1 += wvq.z * b2 + wvq.w * b3;
      }
      float a = acc0 + acc1 + xv;
      float v1 = __shfl(a, qb | 1);
      float v2 = __shfl(a, qb | 2);
      float v3 = __shfl(a, qb | 3);
      if (gt == 0) {
        float si = 1.f / (1.f + expf(-a));   // i
        float sf = 1.f / (1.f + expf(-v1));  // f
        float so = 1.f / (1.f + expf(-v3));  // o
        c = sf * c + si * tanhf(v2);         // g = v2
        float h = so * tanhf(c);
        hdst[unit] = h;
        out[(size_t)(t * B_ + b) * 512 + d * 256 + unit] = h;
      }
    } else {
      if (gt == 0) hdst[unit] = hsrc[unit];  // frozen h copied forward
    }
    __syncthreads();                         // WG fully consumed h_s
    if (tg == 0) {
      __threadfence();                       // agent-scope release of h stores
      __hip_atomic_fetch_add(myc, 1, __ATOMIC_RELEASE, __HIP_MEMORY_SCOPE_AGENT);
    }
  }
  if (gt == 0)                               // pack_padded: padded outputs zero
    for (int t = len; t < T_; ++t)
      out[(size_t)(t * B_ + b) * 512 + d * 256 + unit] = 0.f;
}

// ---------------- Viterbi (one wave per batch; ref fp-op order) ----------------
__global__ __launch_bounds__(64) void viterbi(
    const float* __restrict__ emis, const float* __restrict__ trans,
    const float* __restrict__ startv, const float* __restrict__ endv,
    const int* __restrict__ lens, int* __restrict__ outp) {
  int b = blockIdx.x, lane = threadIdx.x;
  __shared__ float tr[KTAG * KTAG];
  __shared__ float fin[KTAG];
  __shared__ unsigned char hist[T_ * KTAG];
  for (int i = lane; i < KTAG * KTAG; i += 64) tr[i] = trans[i];
  int len = lens[b];
  float score = (lane < KTAG) ? startv[lane] + emis[(size_t)b * 64 + lane] : -3e38f;
  __syncthreads();
  for (int t = 1; t < len; ++t) {
    float e = (lane < KTAG) ? emis[(size_t)(t * B_ + b) * 64 + lane] : 0.f;
    float best = -3e38f; int bp = 0;
    for (int p = 0; p < KTAG; ++p) {         // ascending p + strict '>': first-index
      float cand = (__shfl(score, p) + tr[p * KTAG + lane]) + e;  // ref op order
      if (cand > best) { best = cand; bp = p; }
    }
    if (lane < KTAG) { score = best; hist[t * KTAG + lane] = (unsigned char)bp; }
  }
  if (lane < KTAG) fin[lane] = score + endv[lane];
  __syncthreads();
  if (lane == 0) {
    float bb = -3e38f; int tag = 0;
    for (int p = 0; p < KTAG; ++p)
      if (fin[p] > bb) { bb = fin[p]; tag = p; }
    for (int t = len - 1; t >= 1; --t) {
      outp[t * B_ + b] = tag;
      tag = hist[t * KTAG + tag];
    }
    outp[b] = tag;
  }
  for (int t = len + lane; t < T_; t += 64) outp[t * B_ + b] = 0;
}

// ---------------- diagnostics (slim) ----------------
__global__ void sentinel_fill(int* __restrict__ outp, int val) {
  int i = blockIdx.x * 256 + threadIdx.x;
  if (i < TB_) outp[i] = val;
}
__global__ void diag_init(int* __restrict__ f) { if (threadIdx.x == 0) f[0] = 0; }
__global__ void check_nan(const float* __restrict__ p, long n, int* __restrict__ f) {
  long i0 = (long)blockIdx.x * 256 + threadIdx.x;
  int bad = 0;
  for (long i = i0; i < n; i += (long)gridDim.x * 256)
    if (!(fabsf(p[i]) <= 1e8f)) bad = 1;
  if (bad) atomicOr(&f[0], 1);
}
__global__ void verdict(const int* __restrict__ f, int* __restrict__ outp) {
  if (f[0]) outp[threadIdx.x] = -4096;
}

// ---------------- host ----------------

extern "C" void kernel_launch(void* const* d_in, const int* in_sizes, int n_in,
                              void* d_out, int out_size, void* d_ws, size_t ws_size,
                              hipStream_t stream) {
  int* outp = (int*)d_out;

  static const int exp_sizes[14] = {16384, 64, 15000000, 614400, 524288, 2048,
                                    1048576, 524288, 2048, 10240, 20, 400, 20, 20};
  int badi = (n_in == 14) ? -1 : 14;
  if (badi < 0)
    for (int i = 0; i < 14; ++i)
      if (in_sizes[i] != exp_sizes[i]) { badi = i; break; }
  if (badi >= 0) {
    hipLaunchKernelGGL(sentinel_fill, dim3((TB_ + 255) / 256), dim3(256), 0, stream,
                       outp, -(20000 + badi));
    return;
  }

  const int*   x      = (const int*)d_in[0];
  const int*   lens   = (const int*)d_in[1];
  const float* emb    = (const float*)d_in[2];
  const float* Wih0   = (const float*)d_in[3];
  const float* Whh0   = (const float*)d_in[4];
  const float* b0     = (const float*)d_in[5];
  const float* Wih1   = (const float*)d_in[6];
  const float* Whh1   = (const float*)d_in[7];
  const float* b1     = (const float*)d_in[8];
  const float* Wout   = (const float*)d_in[9];
  const float* bout   = (const float*)d_in[10];
  const float* trans  = (const float*)d_in[11];
  const float* startv = (const float*)d_in[12];
  const float* endv   = (const float*)d_in[13];

  const size_t sz_whh = (size_t)524288 * 4;   // 2 MiB per layer

  const size_t need =
      (size_t)TB_ * 2048 * 4      // xg
    + (size_t)TB_ * EPAD * 4     // xsA
    + (size_t)TB_ * 512 * 4      // outh
    + (size_t)2048 * EPAD * 4    // B0t
    + (size_t)64 * 512 * 4       // Bot
    + 2 * sz_whh                 // whh0S + whh1S
    + 64 * 4                     // biaso
    + (size_t)TB_ * 64 * 4       // emis
    + (size_t)65536 * 4          // Hg [2][2][64][256]
    + 64 * 4                     // ctr
    + 64;                        // diag

  if (ws_size < need) {
    hipLaunchKernelGGL(sentinel_fill, dim3((TB_ + 255) / 256), dim3(256), 0, stream,
                       outp, -(int)(10000 + (ws_size >> 20)));
    return;
  }

  char* w = (char*)d_ws;
  float* xg    = (float*)w;  w += (size_t)TB_ * 2048 * 4;
  float* xsA   = (float*)w;  w += (size_t)TB_ * EPAD * 4;
  float* outh  = (float*)w;  w += (size_t)TB_ * 512 * 4;
  float* B0t   = (float*)w;  w += (size_t)2048 * EPAD * 4;
  float* Bot   = (float*)w;  w += (size_t)64 * 512 * 4;
  float* whh0S = (float*)w;  w += sz_whh;
  float* whh1S = (float*)w;  w += sz_whh;
  float* biaso = (float*)w;  w += 64 * 4;
  float* emis  = (float*)w;  w += (size_t)TB_ * 64 * 4;
  float* Hg    = (float*)w;  w += (size_t)65536 * 4;
  int*   ctr   = (int*)w;    w += 64 * 4;
  int*   diag  = (int*)w;    w += 64;

  hipLaunchKernelGGL(diag_init, dim3(1), dim3(64), 0, stream, diag);
  hipLaunchKernelGGL(prep_embed, dim3(TB_), dim3(64), 0, stream, x, emb, xsA);
  hipLaunchKernelGGL(prep_b0t, dim3((2048 * EPAD + 255) / 256), dim3(256), 0, stream, Wih0, B0t);
  hipLaunchKernelGGL(prep_bot64, dim3(128), dim3(256), 0, stream, Wout, Bot, bout, biaso);
  hipLaunchKernelGGL(prep_whh3, dim3(2048), dim3(256), 0, stream, Whh0, whh0S);
  hipLaunchKernelGGL(prep_whh3, dim3(2048), dim3(256), 0, stream, Whh1, whh1S);

  // layer 0
  hipLaunchKernelGGL(gemm_f32, dim3(256 * 32), dim3(256), 0, stream,
                     xsA, EPAD, B0t, EPAD, xg, 2048, b0, 32, EPAD);
  hipLaunchKernelGGL(zero_sync, dim3(129), dim3(256), 0, stream, Hg, ctr);
  hipLaunchKernelGGL(lstm_rec, dim3(256), dim3(512), 0, stream,
                     xg, whh0S, outh, lens, Hg, ctr, diag);
  // layer 1 (Wih1/b1 used directly: [2048][512] row-major, K=512)
  hipLaunchKernelGGL(gemm_f32, dim3(256 * 32), dim3(256), 0, stream,
                     outh, 512, Wih1, 512, xg, 2048, b1, 32, 512);
  hipLaunchKernelGGL(zero_sync, dim3(129), dim3(256), 0, stream, Hg, ctr);
  hipLaunchKernelGGL(lstm_rec, dim3(256), dim3(512), 0, stream,
                     xg, whh1S, outh, lens, Hg, ctr, diag);
  // emissions (N padded to 64) + decode
  hipLaunchKernelGGL(gemm_f32, dim3(256), dim3(256), 0, stream,
                     outh, 512, Bot, 512, emis, 64, biaso, 1, 512);
  hipLaunchKernelGGL(check_nan, dim3(256), dim3(256), 0, stream,
                     emis, (long)TB_ * 64, diag);
  hipLaunchKernelGGL(viterbi, dim3(B_), dim3(64), 0, stream,
                     emis, trans, startv, endv, lens, outp);
  hipLaunchKernelGGL(verdict, dim3(1), dim3(64), 0, stream, diag, outp);
}

// Round 6
// 5254.672 us; speedup vs baseline: 2.0740x; 2.0740x over previous
//
#include <hip/hip_runtime.h>
#include <stdint.h>

// BiLSTM-CRF on gfx950 — fp32 (validated absmax 0.0). R12: register-file math:
// 512 VGPR/SIMD physical; per-thread cap = 512/(waves_per_simd_per_block x
// blocks). 1024-thr WGs cap at 128 (heuristic: 64) -> R6-R10 spills. A 256-thr
// WG (1 wave/SIMD) with flat_work_group_size(256,256)+waves_per_eu(1,1) and NO
// launch_bounds (R10: launch_bounds overrode the attr) raises the cap to 512.
// lstm_rec_hi: thread j owns unit j (all 4 gates, no shfl): QR=25 k-quads x4
// gates = 400 pinned VGPRs + 9 quads in LDS (144 KB) + 30 quads streamed
// (480 KB/step vs R8's 1 MB against the ~135 GB/s per-CU L2 wall).
// Host picks hi only if hipFuncGetAttributes proves no-scratch + >=430 regs;
// else launches the verbatim R8 kernel (proven 1963 us floor).

#define T_ 256
#define B_ 64
#define EPAD 304
#define KTAG 20
#define TB_ (T_ * B_)

// hi partition (global k-quads 0..63, q ascending = FP order of R8 lineage)
#define QRH 25                  // quads resident in VGPRs (k 0..99)
#define QLH 9                   // quads in LDS (k 100..135)
#define QSH 30                  // quads streamed (k 136..255)

// lo (R8) partition
#define KR_LO 64
#define KLQ_LO 3
#define NQS_LO 45
#define WLDS_OFF_LO (2 * KR_LO * 1024)                    // 131072 floats
#define WSTR_OFF_LO (WLDS_OFF_LO + 2 * KLQ_LO * 1024 * 4) // 155648 floats

__device__ __forceinline__ float rlane(float v, int l) {
  return __int_as_float(__builtin_amdgcn_readlane(__float_as_int(v), l));
}

// ---------------- prep ----------------

__global__ void prep_embed(const int* __restrict__ x, const float* __restrict__ emb,
                           float* __restrict__ xsA) {
  int r = blockIdx.x;
  int tok = x[r];
  const float* src = emb + (size_t)tok * 300;
  for (int e = threadIdx.x; e < EPAD; e += 64)
    xsA[(size_t)r * EPAD + e] = (e < 300) ? src[e] : 0.f;
}

__global__ void prep_b0t(const float* __restrict__ Wih0, float* __restrict__ B0t) {
  int idx = blockIdx.x * 256 + threadIdx.x;
  if (idx >= 2048 * EPAD) return;
  int n = idx / EPAD, k = idx % EPAD;
  B0t[idx] = (k < 300) ? Wih0[(size_t)n * 300 + k] : 0.f;
}

__global__ void prep_bot64(const float* __restrict__ Wout, float* __restrict__ Bot,
                           const float* __restrict__ bout, float* __restrict__ biaso) {
  int idx = blockIdx.x * 256 + threadIdx.x;   // 64*512
  int n = idx >> 9, k = idx & 511;
  Bot[idx] = (n < KTAG) ? Wout[(size_t)n * 512 + k] : 0.f;
  if (idx < 64) biaso[idx] = (idx < KTAG) ? bout[idx] : 0.f;
}

// hi layout: whhU[d][q=k/4][gate][j][e]  (quad-major; lane j reads 16B at j*16)
__global__ void prep_whh4(const float* __restrict__ Whh, float* __restrict__ whhU) {
  int idx = blockIdx.x * 256 + threadIdx.x;   // 524288
  int d = idx >> 18, rem = idx & 262143, row = rem >> 8, k = rem & 255;
  float v = Whh[(size_t)d * 262144 + (size_t)row * 256 + k];
  int gt = row >> 8, j = row & 255;
  int q = k >> 2, e = k & 3;
  whhU[((((size_t)d * 64 + q) * 4 + gt) * 256 + j) * 4 + e] = v;
}

// lo layout (R8): thread tg owns row (tg&3)*256 + (tg>>2)
__global__ void prep_whh2(const float* __restrict__ Whh, float* __restrict__ whhL) {
  int idx = blockIdx.x * 256 + threadIdx.x;   // 524288
  int d = idx >> 18, rem = idx & 262143, k = rem >> 10, tg = rem & 1023;
  int row = (tg & 3) * 256 + (tg >> 2);
  float v = Whh[(size_t)d * 262144 + (size_t)row * 256 + k];
  if (k < KR_LO) {
    whhL[(size_t)(d * KR_LO + k) * 1024 + tg] = v;
  } else if (k < KR_LO + 12) {
    int kk = k - KR_LO, q = kk >> 2, e = kk & 3;
    whhL[WLDS_OFF_LO + (size_t)((d * KLQ_LO + q) * 1024 + tg) * 4 + e] = v;
  } else {
    int kk = k - KR_LO - 12, q = kk >> 2, e = kk & 3;
    whhL[WSTR_OFF_LO + (size_t)((d * NQS_LO + q) * 1024 + tg) * 4 + e] = v;
  }
}

// ---------------- fp32 GEMM: C[M,N] = A[M,K] * Bt[N,K]^T + bias ----------------
__global__ __launch_bounds__(256) void gemm_f32(
    const float* __restrict__ A, int lda, const float* __restrict__ Bt, int ldb,
    float* __restrict__ C, int ldc, const float* __restrict__ bias,
    int ntn, int K) {
  const int tm = blockIdx.x / ntn, tn = blockIdx.x % ntn;
  const int m0 = tm * 64, n0 = tn * 64;
  __shared__ __align__(16) float As[16][64];
  __shared__ __align__(16) float Bs[16][64];
  const int tid = threadIdx.x;
  const int mm = tid >> 2, kq = (tid & 3) * 4;
  const int tx = tid & 15, ty = tid >> 4;
  float acc[4][4] = {};
  for (int k0 = 0; k0 < K; k0 += 16) {
    float4 av = *(const float4*)&A[(size_t)(m0 + mm) * lda + k0 + kq];
    float4 bv = *(const float4*)&Bt[(size_t)(n0 + mm) * ldb + k0 + kq];
    __syncthreads();                       // guard prev-iter LDS reads
    As[kq + 0][mm] = av.x; As[kq + 1][mm] = av.y;
    As[kq + 2][mm] = av.z; As[kq + 3][mm] = av.w;
    Bs[kq + 0][mm] = bv.x; Bs[kq + 1][mm] = bv.y;
    Bs[kq + 2][mm] = bv.z; Bs[kq + 3][mm] = bv.w;
    __syncthreads();
#pragma unroll
    for (int kk = 0; kk < 16; ++kk) {
      float4 a4 = *(const float4*)&As[kk][ty * 4];
      float4 b4 = *(const float4*)&Bs[kk][tx * 4];
      acc[0][0] += a4.x * b4.x; acc[0][1] += a4.x * b4.y;
      acc[0][2] += a4.x * b4.z; acc[0][3] += a4.x * b4.w;
      acc[1][0] += a4.y * b4.x; acc[1][1] += a4.y * b4.y;
      acc[1][2] += a4.y * b4.z; acc[1][3] += a4.y * b4.w;
      acc[2][0] += a4.z * b4.x; acc[2][1] += a4.z * b4.y;
      acc[2][2] += a4.z * b4.z; acc[2][3] += a4.z * b4.w;
      acc[3][0] += a4.w * b4.x; acc[3][1] += a4.w * b4.y;
      acc[3][2] += a4.w * b4.z; acc[3][3] += a4.w * b4.w;
    }
  }
#pragma unroll
  for (int i = 0; i < 4; ++i)
#pragma unroll
    for (int j = 0; j < 4; ++j)
      C[(size_t)(m0 + ty * 4 + i) * ldc + n0 + tx * 4 + j] =
          acc[i][j] + bias[n0 + tx * 4 + j];
}

// ---------------- hi LSTM: 256 thr, thread j = unit j, all 4 gates ----------
__global__ __attribute__((amdgpu_flat_work_group_size(256, 256),
                          amdgpu_waves_per_eu(1, 1)))
void lstm_rec_hi(const float* __restrict__ xg, const float* __restrict__ whhU,
                 float* __restrict__ out, const int* __restrict__ lens) {
  const int wg = blockIdx.x, d = wg & 1, b = wg >> 1;
  const int len = lens[b];
  const int j = threadIdx.x;               // unit 0..255
  const int l = j & 63;                    // lane
  const float* wb = whhU + (size_t)d * 64 * 4096;  // quad stride 4096 floats

  // resident quads 0..QRH-1 (400 VGPRs), pinned against remat/spill games
  float4 wr[QRH][4];
#pragma unroll
  for (int q = 0; q < QRH; ++q)
#pragma unroll
    for (int g = 0; g < 4; ++g)
      wr[q][g] = *(const float4*)(wb + ((size_t)(q * 4 + g) * 256 + j) * 4);
#pragma unroll
  for (int q = 0; q < QRH; ++q)
#pragma unroll
    for (int g = 0; g < 4; ++g)
      asm volatile("" : "+v"(wr[q][g].x), "+v"(wr[q][g].y),
                        "+v"(wr[q][g].z), "+v"(wr[q][g].w));

  __shared__ __align__(16) float4 wlds[QLH][4][256];  // 144 KiB, quads QRH..QRH+8
  __shared__ __align__(16) float hsd[2][256];
  for (int i = j; i < QLH * 4 * 256; i += 256) {
    int q3 = i >> 10, g = (i >> 8) & 3, jj = i & 255;
    wlds[q3][g][jj] =
        *(const float4*)(wb + ((size_t)((QRH + q3) * 4 + g) * 256 + jj) * 4);
  }
  hsd[0][j] = 0.f;
  float c = 0.f;
  __syncthreads();

  const float* sp = wb + (size_t)j * 4;    // + (q*4+g)*1024 per access

  for (int s = 0; s < len; ++s) {
    const int t = d ? (len - 1 - s) : s;   // bwd consumes & writes reversed pos
    const int rp = t * B_ + b;
    const size_t xb = (size_t)rp * 2048 + d * 1024 + j;
    float xv0 = xg[xb];
    float xv1 = xg[xb + 256];
    float xv2 = xg[xb + 512];
    float xv3 = xg[xb + 768];
    float4 hv = *(const float4*)&hsd[s & 1][l * 4];  // lane l: h[4l..4l+3]

    float ai0 = 0.f, ai1 = 0.f, af0 = 0.f, af1 = 0.f;
    float ag0 = 0.f, ag1 = 0.f, ao0 = 0.f, ao1 = 0.f;
    // resident quads (global q 0..QRH-1), k ascending = R8 FP order per row
#pragma unroll
    for (int q = 0; q < QRH; ++q) {
      float b0 = rlane(hv.x, q), b1 = rlane(hv.y, q);
      float b2 = rlane(hv.z, q), b3 = rlane(hv.w, q);
      ai0 += wr[q][0].x * b0 + wr[q][0].y * b1; ai1 += wr[q][0].z * b2 + wr[q][0].w * b3;
      af0 += wr[q][1].x * b0 + wr[q][1].y * b1; af1 += wr[q][1].z * b2 + wr[q][1].w * b3;
      ag0 += wr[q][2].x * b0 + wr[q][2].y * b1; ag1 += wr[q][2].z * b2 + wr[q][2].w * b3;
      ao0 += wr[q][3].x * b0 + wr[q][3].y * b1; ao1 += wr[q][3].z * b2 + wr[q][3].w * b3;
    }
    // LDS quads (global q QRH..QRH+QLH-1)
#pragma unroll
    for (int q3 = 0; q3 < QLH; ++q3) {
      int q = QRH + q3;
      float b0 = rlane(hv.x, q), b1 = rlane(hv.y, q);
      float b2 = rlane(hv.z, q), b3 = rlane(hv.w, q);
      float4 wi = wlds[q3][0][j], wf = wlds[q3][1][j];
      float4 wg2 = wlds[q3][2][j], wo = wlds[q3][3][j];
      ai0 += wi.x * b0 + wi.y * b1;  ai1 += wi.z * b2 + wi.w * b3;
      af0 += wf.x * b0 + wf.y * b1;  af1 += wf.z * b2 + wf.w * b3;
      ag0 += wg2.x * b0 + wg2.y * b1; ag1 += wg2.z * b2 + wg2.w * b3;
      ao0 += wo.x * b0 + wo.y * b1;  ao1 += wo.z * b2 + wo.w * b3;
    }
    // streamed quads (global q QRH+QLH..63) from L2
#pragma unroll 5
    for (int qs = 0; qs < QSH; ++qs) {
      int q = QRH + QLH + qs;
      float b0 = rlane(hv.x, q), b1 = rlane(hv.y, q);
      float b2 = rlane(hv.z, q), b3 = rlane(hv.w, q);
      float4 wi = *(const float4*)(sp + (size_t)(q * 4 + 0) * 1024);
      float4 wf = *(const float4*)(sp + (size_t)(q * 4 + 1) * 1024);
      float4 wg2 = *(const float4*)(sp + (size_t)(q * 4 + 2) * 1024);
      float4 wo = *(const float4*)(sp + (size_t)(q * 4 + 3) * 1024);
      ai0 += wi.x * b0 + wi.y * b1;  ai1 += wi.z * b2 + wi.w * b3;
      af0 += wf.x * b0 + wf.y * b1;  af1 += wf.z * b2 + wf.w * b3;
      ag0 += wg2.x * b0 + wg2.y * b1; ag1 += wg2.z * b2 + wg2.w * b3;
      ao0 += wo.x * b0 + wo.y * b1;  ao1 += wo.z * b2 + wo.w * b3;
    }

    float a0 = ai0 + ai1 + xv0;              // i
    float a1 = af0 + af1 + xv1;              // f
    float a2 = ag0 + ag1 + xv2;              // g
    float a3 = ao0 + ao1 + xv3;              // o
    float si = 1.f / (1.f + expf(-a0));
    float sf = 1.f / (1.f + expf(-a1));
    float so = 1.f / (1.f + expf(-a3));
    c = sf * c + si * tanhf(a2);
    float h = so * tanhf(c);
    hsd[(s + 1) & 1][j] = h;
    out[(size_t)rp * 512 + d * 256 + j] = h;
    __syncthreads();                          // one barrier per step
  }
  for (int t = len; t < T_; ++t)              // pack_padded: padded outputs zero
    out[(size_t)(t * B_ + b) * 512 + d * 256 + j] = 0.f;
}

// ---------------- lo LSTM: verbatim R8 (proven 1963 us, absmax 0.0) ----------
__global__ __launch_bounds__(1024, 4) void lstm_rec_lo(
    const float* __restrict__ xg, const float* __restrict__ whhL,
    float* __restrict__ out, const int* __restrict__ lens) {
  const int wg = blockIdx.x, dir = wg & 1, b = wg >> 1;
  const int len = lens[b];
  const int tg = threadIdx.x;
  const int j = tg >> 2, gt = tg & 3;
  const int row = gt * 256 + j;

  float wres[KR_LO];
#pragma unroll
  for (int k = 0; k < KR_LO; ++k)
    wres[k] = whhL[(size_t)(dir * KR_LO + k) * 1024 + tg];

  __shared__ __align__(16) float4 wlds[KLQ_LO][1024];
  __shared__ __align__(16) float hsd[2][256];
#pragma unroll
  for (int q = 0; q < KLQ_LO; ++q)
    wlds[q][tg] = *(const float4*)&whhL[WLDS_OFF_LO + (size_t)((dir * KLQ_LO + q) * 1024 + tg) * 4];
  if (tg < 256) hsd[0][tg] = 0.f;
  float c = 0.f;
  __syncthreads();

  const float* sp = whhL + WSTR_OFF_LO + (size_t)dir * NQS_LO * 4096 + (size_t)tg * 4;
  const int lane = tg & 63, qb = lane & ~3;

  for (int s = 0; s < len; ++s) {
    const int t = dir ? (len - 1 - s) : s;
    const int rp = t * B_ + b;
    float xv = xg[(size_t)rp * 2048 + dir * 1024 + row];
    float4 hv = *(const float4*)&hsd[s & 1][lane * 4];

    float acc0 = 0.f, acc1 = 0.f;
#pragma unroll
    for (int q = 0; q < KR_LO / 4; ++q) {
      float b0 = rlane(hv.x, q), b1 = rlane(hv.y, q);
      float b2 = rlane(hv.z, q), b3 = rlane(hv.w, q);
      acc0 += wres[4 * q + 0] * b0 + wres[4 * q + 1] * b1;
      acc1 += wres[4 * q + 2] * b2 + wres[4 * q + 3] * b3;
    }
#pragma unroll
    for (int q3 = 0; q3 < KLQ_LO; ++q3) {
      int q = KR_LO / 4 + q3;
      float4 wl = wlds[q3][tg];
      float b0 = rlane(hv.x, q), b1 = rlane(hv.y, q);
      float b2 = rlane(hv.z, q), b3 = rlane(hv.w, q);
      acc0 += wl.x * b0 + wl.y * b1;
      acc1 += wl.z * b2 + wl.w * b3;
    }
#pragma unroll 5
    for (int qq = 0; qq < NQS_LO; ++qq) {
      int q = KR_LO / 4 + KLQ_LO + qq;
      float4 wv = *(const float4*)(sp + (size_t)qq * 4096);
      float b0 = rlane(hv.x, q), b1 = rlane(hv.y, q);
      float b2 = rlane(hv.z, q), b3 = rlane(hv.w, q);
      acc0 += wv.x * b0 + wv.y * b1;
      acc1 += wv.z * b2 + wv.w * b3;
    }

    float a = acc0 + acc1 + xv;
    float v1 = __shfl(a, qb | 1);
    float v2 = __shfl(a, qb | 2);
    float v3 = __shfl(a, qb | 3);
    if (gt == 0) {
      float si = 1.f / (1.f + expf(-a));
      float sf = 1.f / (1.f + expf(-v1));
      float so = 1.f / (1.f + expf(-v3));
      c = sf * c + si * tanhf(v2);
      float h = so * tanhf(c);
      hsd[(s + 1) & 1][j] = h;
      out[(size_t)rp * 512 + dir * 256 + j] = h;
    }
    __syncthreads();
  }
  for (int t = len; t < T_; ++t)
    if (gt == 0) out[(size_t)(t * B_ + b) * 512 + dir * 256 + j] = 0.f;
}

// ---------------- Viterbi (one wave per batch; ref fp-op order) ----------------
__global__ __launch_bounds__(64) void viterbi(
    const float* __restrict__ emis, const float* __restrict__ trans,
    const float* __restrict__ startv, const float* __restrict__ endv,
    const int* __restrict__ lens, int* __restrict__ outp) {
  int b = blockIdx.x, lane = threadIdx.x;
  __shared__ float tr[KTAG * KTAG];
  __shared__ float fin[KTAG];
  __shared__ unsigned char hist[T_ * KTAG];
  for (int i = lane; i < KTAG * KTAG; i += 64) tr[i] = trans[i];
  int len = lens[b];
  float score = (lane < KTAG) ? startv[lane] + emis[(size_t)b * 64 + lane] : -3e38f;
  __syncthreads();
  for (int t = 1; t < len; ++t) {
    float e = (lane < KTAG) ? emis[(size_t)(t * B_ + b) * 64 + lane] : 0.f;
    float best = -3e38f; int bp = 0;
    for (int p = 0; p < KTAG; ++p) {         // ascending p + strict '>': first-index
      float cand = (__shfl(score, p) + tr[p * KTAG + lane]) + e;  // ref op order
      if (cand > best) { best = cand; bp = p; }
    }
    if (lane < KTAG) { score = best; hist[t * KTAG + lane] = (unsigned char)bp; }
  }
  if (lane < KTAG) fin[lane] = score + endv[lane];
  __syncthreads();
  if (lane == 0) {
    float bb = -3e38f; int tag = 0;
    for (int p = 0; p < KTAG; ++p)
      if (fin[p] > bb) { bb = fin[p]; tag = p; }
    for (int t = len - 1; t >= 1; --t) {
      outp[t * B_ + b] = tag;
      tag = hist[t * KTAG + tag];
    }
    outp[b] = tag;
  }
  for (int t = len + lane; t < T_; t += 64) outp[t * B_ + b] = 0;
}

// ---------------- diagnostics (slim) ----------------
__global__ void sentinel_fill(int* __restrict__ outp, int val) {
  int i = blockIdx.x * 256 + threadIdx.x;
  if (i < TB_) outp[i] = val;
}
__global__ void diag_init(int* __restrict__ f) { if (threadIdx.x == 0) f[0] = 0; }
__global__ void check_nan(const float* __restrict__ p, long n, int* __restrict__ f) {
  long i0 = (long)blockIdx.x * 256 + threadIdx.x;
  int bad = 0;
  for (long i = i0; i < n; i += (long)gridDim.x * 256)
    if (!(fabsf(p[i]) <= 1e8f)) bad = 1;
  if (bad) atomicOr(&f[0], 1);
}
__global__ void verdict(const int* __restrict__ f, int* __restrict__ outp) {
  if (f[0]) outp[threadIdx.x] = -4096;
}

// ---------------- host ----------------

extern "C" void kernel_launch(void* const* d_in, const int* in_sizes, int n_in,
                              void* d_out, int out_size, void* d_ws, size_t ws_size,
                              hipStream_t stream) {
  int* outp = (int*)d_out;

  static const int exp_sizes[14] = {16384, 64, 15000000, 614400, 524288, 2048,
                                    1048576, 524288, 2048, 10240, 20, 400, 20, 20};
  int badi = (n_in == 14) ? -1 : 14;
  if (badi < 0)
    for (int i = 0; i < 14; ++i)
      if (in_sizes[i] != exp_sizes[i]) { badi = i; break; }
  if (badi >= 0) {
    hipLaunchKernelGGL(sentinel_fill, dim3((TB_ + 255) / 256), dim3(256), 0, stream,
                       outp, -(20000 + badi));
    return;
  }

  const int*   x      = (const int*)d_in[0];
  const int*   lens   = (const int*)d_in[1];
  const float* emb    = (const float*)d_in[2];
  const float* Wih0   = (const float*)d_in[3];
  const float* Whh0   = (const float*)d_in[4];
  const float* b0     = (const float*)d_in[5];
  const float* Wih1   = (const float*)d_in[6];
  const float* Whh1   = (const float*)d_in[7];
  const float* b1     = (const float*)d_in[8];
  const float* Wout   = (const float*)d_in[9];
  const float* bout   = (const float*)d_in[10];
  const float* trans  = (const float*)d_in[11];
  const float* startv = (const float*)d_in[12];
  const float* endv   = (const float*)d_in[13];

  // pick hi path only if the allocator provably granted residency
  static int chosen = -1;
  if (chosen < 0) {
    chosen = 0;
    hipFuncAttributes fa;
    if (hipFuncGetAttributes(&fa, reinterpret_cast<const void*>(&lstm_rec_hi)) ==
            hipSuccess &&
        fa.localSizeBytes == 0 && fa.numRegs >= 430)
      chosen = 1;
  }

  const size_t sz_whh = (size_t)524288 * 4;   // 2 MiB per layer per layout

  const size_t need =
      (size_t)TB_ * 2048 * 4      // xg
    + (size_t)TB_ * EPAD * 4     // xsA
    + (size_t)TB_ * 512 * 4      // outh
    + (size_t)2048 * EPAD * 4    // B0t
    + (size_t)64 * 512 * 4       // Bot
    + 4 * sz_whh                 // whh{0,1} x {U,L}
    + 64 * 4                     // biaso
    + (size_t)TB_ * 64 * 4       // emis
    + 64;                        // diag

  if (ws_size < need) {
    hipLaunchKernelGGL(sentinel_fill, dim3((TB_ + 255) / 256), dim3(256), 0, stream,
                       outp, -(int)(10000 + (ws_size >> 20)));
    return;
  }

  char* w = (char*)d_ws;
  float* xg    = (float*)w;  w += (size_t)TB_ * 2048 * 4;
  float* xsA   = (float*)w;  w += (size_t)TB_ * EPAD * 4;
  float* outh  = (float*)w;  w += (size_t)TB_ * 512 * 4;
  float* B0t   = (float*)w;  w += (size_t)2048 * EPAD * 4;
  float* Bot   = (float*)w;  w += (size_t)64 * 512 * 4;
  float* whh0U = (float*)w;  w += sz_whh;
  float* whh1U = (float*)w;  w += sz_whh;
  float* whh0L = (float*)w;  w += sz_whh;
  float* whh1L = (float*)w;  w += sz_whh;
  float* biaso = (float*)w;  w += 64 * 4;
  float* emis  = (float*)w;  w += (size_t)TB_ * 64 * 4;
  int*   diag  = (int*)w;    w += 64;

  hipLaunchKernelGGL(diag_init, dim3(1), dim3(64), 0, stream, diag);
  hipLaunchKernelGGL(prep_embed, dim3(TB_), dim3(64), 0, stream, x, emb, xsA);
  hipLaunchKernelGGL(prep_b0t, dim3((2048 * EPAD + 255) / 256), dim3(256), 0, stream, Wih0, B0t);
  hipLaunchKernelGGL(prep_bot64, dim3(128), dim3(256), 0, stream, Wout, Bot, bout, biaso);
  if (chosen == 1) {
    hipLaunchKernelGGL(prep_whh4, dim3(2048), dim3(256), 0, stream, Whh0, whh0U);
    hipLaunchKernelGGL(prep_whh4, dim3(2048), dim3(256), 0, stream, Whh1, whh1U);
  } else {
    hipLaunchKernelGGL(prep_whh2, dim3(2048), dim3(256), 0, stream, Whh0, whh0L);
    hipLaunchKernelGGL(prep_whh2, dim3(2048), dim3(256), 0, stream, Whh1, whh1L);
  }

  // layer 0
  hipLaunchKernelGGL(gemm_f32, dim3(256 * 32), dim3(256), 0, stream,
                     xsA, EPAD, B0t, EPAD, xg, 2048, b0, 32, EPAD);
  if (chosen == 1)
    hipLaunchKernelGGL(lstm_rec_hi, dim3(128), dim3(256), 0, stream, xg, whh0U, outh, lens);
  else
    hipLaunchKernelGGL(lstm_rec_lo, dim3(128), dim3(1024), 0, stream, xg, whh0L, outh, lens);
  // layer 1 (Wih1/b1 used directly: [2048][512] row-major, K=512)
  hipLaunchKernelGGL(gemm_f32, dim3(256 * 32), dim3(256), 0, stream,
                     outh, 512, Wih1, 512, xg, 2048, b1, 32, 512);
  if (chosen == 1)
    hipLaunchKernelGGL(lstm_rec_hi, dim3(128), dim3(256), 0, stream, xg, whh1U, outh, lens);
  else
    hipLaunchKernelGGL(lstm_rec_lo, dim3(128), dim3(1024), 0, stream, xg, whh1L, outh, lens);
  // emissions (N padded to 64) + decode
  hipLaunchKernelGGL(gemm_f32, dim3(256), dim3(256), 0, stream,
                     outh, 512, Bot, 512, emis, 64, biaso, 1, 512);
  hipLaunchKernelGGL(check_nan, dim3(256), dim3(256), 0, stream,
                     emis, (long)TB_ * 64, diag);
  hipLaunchKernelGGL(viterbi, dim3(B_), dim3(64), 0, stream,
                     emis, trans, startv, endv, lens, outp);
  hipLaunchKernelGGL(verdict, dim3(1), dim3(64), 0, stream, diag, outp);
}

// Round 7
// 3993.727 us; speedup vs baseline: 2.7289x; 1.3157x over previous
//
#include <hip/hip_runtime.h>
#include <stdint.h>

// BiLSTM-CRF on gfx950 — fp32 (validated absmax 0.0). R13: R12 got residency
// (244 VGPR + AGPR, no scratch) but waves_per_eu(1,1) left 1 wave/SIMD: zero
// TLP, L2 stream latency-serialized at 58 GB/s/CU (R6/R8 with 4 waves/SIMD
// achieved ~135). Optimum is the middle: 512 thr, waves_per_eu(2,2) -> 256-reg
// cap, gate-split (thread (j,gp) owns gate pair i,f or g,o of unit j).
// Per gate-row: 22 quads in regs + 8 in LDS (128 KB) + 34 streamed
// = 544 KB/step (vs R8 1 MB) with 2-wave TLP to actually reach the BW wall.
// Per-gate acc0/acc1 q-ascending chain identical to R8/R12 -> bitwise-same h.
// Fallback: attribute-probe; lo = verbatim R8 (proven 1963 us).

#define T_ 256
#define B_ 64
#define EPAD 304
#define KTAG 20
#define TB_ (T_ * B_)

// hi2 partition (global k-quads 0..63, q ascending)
#define QR2 22                  // quads resident per gate-row (176 VGPRs)
#define QL2 8                   // quads in LDS per gate-row (128 KiB total)
#define QS2 34                  // quads streamed per gate-row

// lo (R8) partition
#define KR_LO 64
#define KLQ_LO 3
#define NQS_LO 45
#define WLDS_OFF_LO (2 * KR_LO * 1024)                    // 131072 floats
#define WSTR_OFF_LO (WLDS_OFF_LO + 2 * KLQ_LO * 1024 * 4) // 155648 floats

__device__ __forceinline__ float rlane(float v, int l) {
  return __int_as_float(__builtin_amdgcn_readlane(__float_as_int(v), l));
}

// ---------------- prep ----------------

__global__ void prep_embed(const int* __restrict__ x, const float* __restrict__ emb,
                           float* __restrict__ xsA) {
  int r = blockIdx.x;
  int tok = x[r];
  const float* src = emb + (size_t)tok * 300;
  for (int e = threadIdx.x; e < EPAD; e += 64)
    xsA[(size_t)r * EPAD + e] = (e < 300) ? src[e] : 0.f;
}

__global__ void prep_b0t(const float* __restrict__ Wih0, float* __restrict__ B0t) {
  int idx = blockIdx.x * 256 + threadIdx.x;
  if (idx >= 2048 * EPAD) return;
  int n = idx / EPAD, k = idx % EPAD;
  B0t[idx] = (k < 300) ? Wih0[(size_t)n * 300 + k] : 0.f;
}

__global__ void prep_bot64(const float* __restrict__ Wout, float* __restrict__ Bot,
                           const float* __restrict__ bout, float* __restrict__ biaso) {
  int idx = blockIdx.x * 256 + threadIdx.x;   // 64*512
  int n = idx >> 9, k = idx & 511;
  Bot[idx] = (n < KTAG) ? Wout[(size_t)n * 512 + k] : 0.f;
  if (idx < 64) biaso[idx] = (idx < KTAG) ? bout[idx] : 0.f;
}

// hi layout: whhU[d][q=k/4][gate][j][e]  (quad-major; lane j reads 16B at j*16)
__global__ void prep_whh4(const float* __restrict__ Whh, float* __restrict__ whhU) {
  int idx = blockIdx.x * 256 + threadIdx.x;   // 524288
  int d = idx >> 18, rem = idx & 262143, row = rem >> 8, k = rem & 255;
  float v = Whh[(size_t)d * 262144 + (size_t)row * 256 + k];
  int gt = row >> 8, j = row & 255;
  int q = k >> 2, e = k & 3;
  whhU[((((size_t)d * 64 + q) * 4 + gt) * 256 + j) * 4 + e] = v;
}

// lo layout (R8): thread tg owns row (tg&3)*256 + (tg>>2)
__global__ void prep_whh2(const float* __restrict__ Whh, float* __restrict__ whhL) {
  int idx = blockIdx.x * 256 + threadIdx.x;   // 524288
  int d = idx >> 18, rem = idx & 262143, k = rem >> 10, tg = rem & 1023;
  int row = (tg & 3) * 256 + (tg >> 2);
  float v = Whh[(size_t)d * 262144 + (size_t)row * 256 + k];
  if (k < KR_LO) {
    whhL[(size_t)(d * KR_LO + k) * 1024 + tg] = v;
  } else if (k < KR_LO + 12) {
    int kk = k - KR_LO, q = kk >> 2, e = kk & 3;
    whhL[WLDS_OFF_LO + (size_t)((d * KLQ_LO + q) * 1024 + tg) * 4 + e] = v;
  } else {
    int kk = k - KR_LO - 12, q = kk >> 2, e = kk & 3;
    whhL[WSTR_OFF_LO + (size_t)((d * NQS_LO + q) * 1024 + tg) * 4 + e] = v;
  }
}

// ---------------- fp32 GEMM: C[M,N] = A[M,K] * Bt[N,K]^T + bias ----------------
__global__ __launch_bounds__(256) void gemm_f32(
    const float* __restrict__ A, int lda, const float* __restrict__ Bt, int ldb,
    float* __restrict__ C, int ldc, const float* __restrict__ bias,
    int ntn, int K) {
  const int tm = blockIdx.x / ntn, tn = blockIdx.x % ntn;
  const int m0 = tm * 64, n0 = tn * 64;
  __shared__ __align__(16) float As[16][64];
  __shared__ __align__(16) float Bs[16][64];
  const int tid = threadIdx.x;
  const int mm = tid >> 2, kq = (tid & 3) * 4;
  const int tx = tid & 15, ty = tid >> 4;
  float acc[4][4] = {};
  for (int k0 = 0; k0 < K; k0 += 16) {
    float4 av = *(const float4*)&A[(size_t)(m0 + mm) * lda + k0 + kq];
    float4 bv = *(const float4*)&Bt[(size_t)(n0 + mm) * ldb + k0 + kq];
    __syncthreads();                       // guard prev-iter LDS reads
    As[kq + 0][mm] = av.x; As[kq + 1][mm] = av.y;
    As[kq + 2][mm] = av.z; As[kq + 3][mm] = av.w;
    Bs[kq + 0][mm] = bv.x; Bs[kq + 1][mm] = bv.y;
    Bs[kq + 2][mm] = bv.z; Bs[kq + 3][mm] = bv.w;
    __syncthreads();
#pragma unroll
    for (int kk = 0; kk < 16; ++kk) {
      float4 a4 = *(const float4*)&As[kk][ty * 4];
      float4 b4 = *(const float4*)&Bs[kk][tx * 4];
      acc[0][0] += a4.x * b4.x; acc[0][1] += a4.x * b4.y;
      acc[0][2] += a4.x * b4.z; acc[0][3] += a4.x * b4.w;
      acc[1][0] += a4.y * b4.x; acc[1][1] += a4.y * b4.y;
      acc[1][2] += a4.y * b4.z; acc[1][3] += a4.y * b4.w;
      acc[2][0] += a4.z * b4.x; acc[2][1] += a4.z * b4.y;
      acc[2][2] += a4.z * b4.z; acc[2][3] += a4.z * b4.w;
      acc[3][0] += a4.w * b4.x; acc[3][1] += a4.w * b4.y;
      acc[3][2] += a4.w * b4.z; acc[3][3] += a4.w * b4.w;
    }
  }
#pragma unroll
  for (int i = 0; i < 4; ++i)
#pragma unroll
    for (int j = 0; j < 4; ++j)
      C[(size_t)(m0 + ty * 4 + i) * ldc + n0 + tx * 4 + j] =
          acc[i][j] + bias[n0 + tx * 4 + j];
}

// ---------------- hi2 LSTM: 512 thr, thread (j,gp) = unit j, gates 2gp,2gp+1 --
__global__ __attribute__((amdgpu_flat_work_group_size(512, 512),
                          amdgpu_waves_per_eu(2, 2)))
void lstm_rec_hi2(const float* __restrict__ xg, const float* __restrict__ whhU,
                  float* __restrict__ out, const int* __restrict__ lens) {
  const int wg = blockIdx.x, d = wg & 1, b = wg >> 1;
  const int len = lens[b];
  const int tg = threadIdx.x;
  const int j = tg & 255, gp = tg >> 8;    // gp 0: gates i,f ; gp 1: gates g,o
  const int g0 = gp * 2;
  const int l = tg & 63;
  const float* wb = whhU + (size_t)d * 64 * 4096;  // ((q*4+g)*256 + j)*4 floats

  // resident quads 0..QR2-1 for both gate-rows (176 VGPRs), pinned
  float4 wA[QR2], wB[QR2];
#pragma unroll
  for (int q = 0; q < QR2; ++q) {
    wA[q] = *(const float4*)(wb + ((size_t)(q * 4 + g0) * 256 + j) * 4);
    wB[q] = *(const float4*)(wb + ((size_t)(q * 4 + g0 + 1) * 256 + j) * 4);
  }
#pragma unroll
  for (int q = 0; q < QR2; ++q) {
    asm volatile("" : "+v"(wA[q].x), "+v"(wA[q].y), "+v"(wA[q].z), "+v"(wA[q].w));
    asm volatile("" : "+v"(wB[q].x), "+v"(wB[q].y), "+v"(wB[q].z), "+v"(wB[q].w));
  }

  __shared__ __align__(16) float4 wlds[QL2][4][256];  // 128 KiB, quads QR2..QR2+7
  __shared__ __align__(16) float hsd[2][256];
  __shared__ __align__(8) float2 exch[256];
  for (int i = tg; i < QL2 * 4 * 256; i += 512) {
    int q3 = i >> 10, g = (i >> 8) & 3, jj = i & 255;
    wlds[q3][g][jj] =
        *(const float4*)(wb + ((size_t)((QR2 + q3) * 4 + g) * 256 + jj) * 4);
  }
  if (tg < 256) hsd[0][tg] = 0.f;
  float c = 0.f;
  __syncthreads();

  for (int s = 0; s < len; ++s) {
    const int t = d ? (len - 1 - s) : s;   // bwd consumes & writes reversed pos
    const int rp = t * B_ + b;
    const size_t xb = (size_t)rp * 2048 + d * 1024 + (size_t)g0 * 256 + j;
    float xv0 = xg[xb];                    // gate g0 row
    float xv1 = xg[xb + 256];              // gate g0+1 row
    float4 hv = *(const float4*)&hsd[s & 1][l * 4];  // lane l: h[4l..4l+3]

    float aA0 = 0.f, aA1 = 0.f, aB0 = 0.f, aB1 = 0.f;
    // resident quads (q 0..QR2-1), k ascending = validated FP chain
#pragma unroll
    for (int q = 0; q < QR2; ++q) {
      float b0 = rlane(hv.x, q), b1 = rlane(hv.y, q);
      float b2 = rlane(hv.z, q), b3 = rlane(hv.w, q);
      aA0 += wA[q].x * b0 + wA[q].y * b1;  aA1 += wA[q].z * b2 + wA[q].w * b3;
      aB0 += wB[q].x * b0 + wB[q].y * b1;  aB1 += wB[q].z * b2 + wB[q].w * b3;
    }
    // LDS quads (q QR2..QR2+QL2-1)
#pragma unroll
    for (int q3 = 0; q3 < QL2; ++q3) {
      int q = QR2 + q3;
      float b0 = rlane(hv.x, q), b1 = rlane(hv.y, q);
      float b2 = rlane(hv.z, q), b3 = rlane(hv.w, q);
      float4 wa = wlds[q3][g0][j], wbq = wlds[q3][g0 + 1][j];
      aA0 += wa.x * b0 + wa.y * b1;   aA1 += wa.z * b2 + wa.w * b3;
      aB0 += wbq.x * b0 + wbq.y * b1; aB1 += wbq.z * b2 + wbq.w * b3;
    }
    // streamed quads (q QR2+QL2..63) from L2
#pragma unroll 2
    for (int qs = 0; qs < QS2; ++qs) {
      int q = QR2 + QL2 + qs;
      float4 wa = *(const float4*)(wb + ((size_t)(q * 4 + g0) * 256 + j) * 4);
      float4 wbq = *(const float4*)(wb + ((size_t)(q * 4 + g0 + 1) * 256 + j) * 4);
      float b0 = rlane(hv.x, q), b1 = rlane(hv.y, q);
      float b2 = rlane(hv.z, q), b3 = rlane(hv.w, q);
      aA0 += wa.x * b0 + wa.y * b1;   aA1 += wa.z * b2 + wa.w * b3;
      aB0 += wbq.x * b0 + wbq.y * b1; aB1 += wbq.z * b2 + wbq.w * b3;
    }

    float aA = aA0 + aA1 + xv0;            // gp0: i ; gp1: g
    float aB = aB0 + aB1 + xv1;            // gp0: f ; gp1: o
    if (gp == 1) exch[j] = make_float2(aA, aB);
    __syncthreads();                        // exch visible
    if (gp == 0) {
      float2 go = exch[j];
      float si = 1.f / (1.f + expf(-aA));  // i
      float sf = 1.f / (1.f + expf(-aB));  // f
      float so = 1.f / (1.f + expf(-go.y));// o
      c = sf * c + si * tanhf(go.x);       // g
      float h = so * tanhf(c);
      hsd[(s + 1) & 1][j] = h;
      out[(size_t)rp * 512 + d * 256 + j] = h;
    }
    __syncthreads();                        // h_s+1 visible, exch reusable
  }
  if (gp == 0)                              // pack_padded: padded outputs zero
    for (int t = len; t < T_; ++t)
      out[(size_t)(t * B_ + b) * 512 + d * 256 + j] = 0.f;
}

// ---------------- lo LSTM: verbatim R8 (proven 1963 us, absmax 0.0) ----------
__global__ __launch_bounds__(1024, 4) void lstm_rec_lo(
    const float* __restrict__ xg, const float* __restrict__ whhL,
    float* __restrict__ out, const int* __restrict__ lens) {
  const int wg = blockIdx.x, dir = wg & 1, b = wg >> 1;
  const int len = lens[b];
  const int tg = threadIdx.x;
  const int j = tg >> 2, gt = tg & 3;
  const int row = gt * 256 + j;

  float wres[KR_LO];
#pragma unroll
  for (int k = 0; k < KR_LO; ++k)
    wres[k] = whhL[(size_t)(dir * KR_LO + k) * 1024 + tg];

  __shared__ __align__(16) float4 wlds[KLQ_LO][1024];
  __shared__ __align__(16) float hsd[2][256];
#pragma unroll
  for (int q = 0; q < KLQ_LO; ++q)
    wlds[q][tg] = *(const float4*)&whhL[WLDS_OFF_LO + (size_t)((dir * KLQ_LO + q) * 1024 + tg) * 4];
  if (tg < 256) hsd[0][tg] = 0.f;
  float c = 0.f;
  __syncthreads();

  const float* sp = whhL + WSTR_OFF_LO + (size_t)dir * NQS_LO * 4096 + (size_t)tg * 4;
  const int lane = tg & 63, qb = lane & ~3;

  for (int s = 0; s < len; ++s) {
    const int t = dir ? (len - 1 - s) : s;
    const int rp = t * B_ + b;
    float xv = xg[(size_t)rp * 2048 + dir * 1024 + row];
    float4 hv = *(const float4*)&hsd[s & 1][lane * 4];

    float acc0 = 0.f, acc1 = 0.f;
#pragma unroll
    for (int q = 0; q < KR_LO / 4; ++q) {
      float b0 = rlane(hv.x, q), b1 = rlane(hv.y, q);
      float b2 = rlane(hv.z, q), b3 = rlane(hv.w, q);
      acc0 += wres[4 * q + 0] * b0 + wres[4 * q + 1] * b1;
      acc1 += wres[4 * q + 2] * b2 + wres[4 * q + 3] * b3;
    }
#pragma unroll
    for (int q3 = 0; q3 < KLQ_LO; ++q3) {
      int q = KR_LO / 4 + q3;
      float4 wl = wlds[q3][tg];
      float b0 = rlane(hv.x, q), b1 = rlane(hv.y, q);
      float b2 = rlane(hv.z, q), b3 = rlane(hv.w, q);
      acc0 += wl.x * b0 + wl.y * b1;
      acc1 += wl.z * b2 + wl.w * b3;
    }
#pragma unroll 5
    for (int qq = 0; qq < NQS_LO; ++qq) {
      int q = KR_LO / 4 + KLQ_LO + qq;
      float4 wv = *(const float4*)(sp + (size_t)qq * 4096);
      float b0 = rlane(hv.x, q), b1 = rlane(hv.y, q);
      float b2 = rlane(hv.z, q), b3 = rlane(hv.w, q);
      acc0 += wv.x * b0 + wv.y * b1;
      acc1 += wv.z * b2 + wv.w * b3;
    }

    float a = acc0 + acc1 + xv;
    float v1 = __shfl(a, qb | 1);
    float v2 = __shfl(a, qb | 2);
    float v3 = __shfl(a, qb | 3);
    if (gt == 0) {
      float si = 1.f / (1.f + expf(-a));
      float sf = 1.f / (1.f + expf(-v1));
      float so = 1.f / (1.f + expf(-v3));
      c = sf * c + si * tanhf(v2);
      float h = so * tanhf(c);
      hsd[(s + 1) & 1][j] = h;
      out[(size_t)rp * 512 + dir * 256 + j] = h;
    }
    __syncthreads();
  }
  for (int t = len; t < T_; ++t)
    if (gt == 0) out[(size_t)(t * B_ + b) * 512 + dir * 256 + j] = 0.f;
}

// ---------------- Viterbi (one wave per batch; ref fp-op order) ----------------
__global__ __launch_bounds__(64) void viterbi(
    const float* __restrict__ emis, const float* __restrict__ trans,
    const float* __restrict__ startv, const float* __restrict__ endv,
    const int* __restrict__ lens, int* __restrict__ outp) {
  int b = blockIdx.x, lane = threadIdx.x;
  __shared__ float tr[KTAG * KTAG];
  __shared__ float fin[KTAG];
  __shared__ unsigned char hist[T_ * KTAG];
  for (int i = lane; i < KTAG * KTAG; i += 64) tr[i] = trans[i];
  int len = lens[b];
  float score = (lane < KTAG) ? startv[lane] + emis[(size_t)b * 64 + lane] : -3e38f;
  __syncthreads();
  for (int t = 1; t < len; ++t) {
    float e = (lane < KTAG) ? emis[(size_t)(t * B_ + b) * 64 + lane] : 0.f;
    float best = -3e38f; int bp = 0;
    for (int p = 0; p < KTAG; ++p) {         // ascending p + strict '>': first-index
      float cand = (__shfl(score, p) + tr[p * KTAG + lane]) + e;  // ref op order
      if (cand > best) { best = cand; bp = p; }
    }
    if (lane < KTAG) { score = best; hist[t * KTAG + lane] = (unsigned char)bp; }
  }
  if (lane < KTAG) fin[lane] = score + endv[lane];
  __syncthreads();
  if (lane == 0) {
    float bb = -3e38f; int tag = 0;
    for (int p = 0; p < KTAG; ++p)
      if (fin[p] > bb) { bb = fin[p]; tag = p; }
    for (int t = len - 1; t >= 1; --t) {
      outp[t * B_ + b] = tag;
      tag = hist[t * KTAG + tag];
    }
    outp[b] = tag;
  }
  for (int t = len + lane; t < T_; t += 64) outp[t * B_ + b] = 0;
}

// ---------------- diagnostics (slim) ----------------
__global__ void sentinel_fill(int* __restrict__ outp, int val) {
  int i = blockIdx.x * 256 + threadIdx.x;
  if (i < TB_) outp[i] = val;
}
__global__ void diag_init(int* __restrict__ f) { if (threadIdx.x == 0) f[0] = 0; }
__global__ void check_nan(const float* __restrict__ p, long n, int* __restrict__ f) {
  long i0 = (long)blockIdx.x * 256 + threadIdx.x;
  int bad = 0;
  for (long i = i0; i < n; i += (long)gridDim.x * 256)
    if (!(fabsf(p[i]) <= 1e8f)) bad = 1;
  if (bad) atomicOr(&f[0], 1);
}
__global__ void verdict(const int* __restrict__ f, int* __restrict__ outp) {
  if (f[0]) outp[threadIdx.x] = -4096;
}

// ---------------- host ----------------

extern "C" void kernel_launch(void* const* d_in, const int* in_sizes, int n_in,
                              void* d_out, int out_size, void* d_ws, size_t ws_size,
                              hipStream_t stream) {
  int* outp = (int*)d_out;

  static const int exp_sizes[14] = {16384, 64, 15000000, 614400, 524288, 2048,
                                    1048576, 524288, 2048, 10240, 20, 400, 20, 20};
  int badi = (n_in == 14) ? -1 : 14;
  if (badi < 0)
    for (int i = 0; i < 14; ++i)
      if (in_sizes[i] != exp_sizes[i]) { badi = i; break; }
  if (badi >= 0) {
    hipLaunchKernelGGL(sentinel_fill, dim3((TB_ + 255) / 256), dim3(256), 0, stream,
                       outp, -(20000 + badi));
    return;
  }

  const int*   x      = (const int*)d_in[0];
  const int*   lens   = (const int*)d_in[1];
  const float* emb    = (const float*)d_in[2];
  const float* Wih0   = (const float*)d_in[3];
  const float* Whh0   = (const float*)d_in[4];
  const float* b0     = (const float*)d_in[5];
  const float* Wih1   = (const float*)d_in[6];
  const float* Whh1   = (const float*)d_in[7];
  const float* b1     = (const float*)d_in[8];
  const float* Wout   = (const float*)d_in[9];
  const float* bout   = (const float*)d_in[10];
  const float* trans  = (const float*)d_in[11];
  const float* startv = (const float*)d_in[12];
  const float* endv   = (const float*)d_in[13];

  // pick hi2 only if the allocator provably granted residency (no scratch,
  // real register allocation); else lo (verbatim R8 floor).
  static int chosen = -1;
  if (chosen < 0) {
    chosen = 0;
    hipFuncAttributes fa;
    if (hipFuncGetAttributes(&fa, reinterpret_cast<const void*>(&lstm_rec_hi2)) ==
            hipSuccess &&
        fa.localSizeBytes == 0 && fa.numRegs >= 160)
      chosen = 1;
  }

  const size_t sz_whh = (size_t)524288 * 4;   // 2 MiB per layer per layout

  const size_t need =
      (size_t)TB_ * 2048 * 4      // xg
    + (size_t)TB_ * EPAD * 4     // xsA
    + (size_t)TB_ * 512 * 4      // outh
    + (size_t)2048 * EPAD * 4    // B0t
    + (size_t)64 * 512 * 4       // Bot
    + 4 * sz_whh                 // whh{0,1} x {U,L}
    + 64 * 4                     // biaso
    + (size_t)TB_ * 64 * 4       // emis
    + 64;                        // diag

  if (ws_size < need) {
    hipLaunchKernelGGL(sentinel_fill, dim3((TB_ + 255) / 256), dim3(256), 0, stream,
                       outp, -(int)(10000 + (ws_size >> 20)));
    return;
  }

  char* w = (char*)d_ws;
  float* xg    = (float*)w;  w += (size_t)TB_ * 2048 * 4;
  float* xsA   = (float*)w;  w += (size_t)TB_ * EPAD * 4;
  float* outh  = (float*)w;  w += (size_t)TB_ * 512 * 4;
  float* B0t   = (float*)w;  w += (size_t)2048 * EPAD * 4;
  float* Bot   = (float*)w;  w += (size_t)64 * 512 * 4;
  float* whh0U = (float*)w;  w += sz_whh;
  float* whh1U = (float*)w;  w += sz_whh;
  float* whh0L = (float*)w;  w += sz_whh;
  float* whh1L = (float*)w;  w += sz_whh;
  float* biaso = (float*)w;  w += 64 * 4;
  float* emis  = (float*)w;  w += (size_t)TB_ * 64 * 4;
  int*   diag  = (int*)w;    w += 64;

  hipLaunchKernelGGL(diag_init, dim3(1), dim3(64), 0, stream, diag);
  hipLaunchKernelGGL(prep_embed, dim3(TB_), dim3(64), 0, stream, x, emb, xsA);
  hipLaunchKernelGGL(prep_b0t, dim3((2048 * EPAD + 255) / 256), dim3(256), 0, stream, Wih0, B0t);
  hipLaunchKernelGGL(prep_bot64, dim3(128), dim3(256), 0, stream, Wout, Bot, bout, biaso);
  if (chosen == 1) {
    hipLaunchKernelGGL(prep_whh4, dim3(2048), dim3(256), 0, stream, Whh0, whh0U);
    hipLaunchKernelGGL(prep_whh4, dim3(2048), dim3(256), 0, stream, Whh1, whh1U);
  } else {
    hipLaunchKernelGGL(prep_whh2, dim3(2048), dim3(256), 0, stream, Whh0, whh0L);
    hipLaunchKernelGGL(prep_whh2, dim3(2048), dim3(256), 0, stream, Whh1, whh1L);
  }

  // layer 0
  hipLaunchKernelGGL(gemm_f32, dim3(256 * 32), dim3(256), 0, stream,
                     xsA, EPAD, B0t, EPAD, xg, 2048, b0, 32, EPAD);
  if (chosen == 1)
    hipLaunchKernelGGL(lstm_rec_hi2, dim3(128), dim3(512), 0, stream, xg, whh0U, outh, lens);
  else
    hipLaunchKernelGGL(lstm_rec_lo, dim3(128), dim3(1024), 0, stream, xg, whh0L, outh, lens);
  // layer 1 (Wih1/b1 used directly: [2048][512] row-major, K=512)
  hipLaunchKernelGGL(gemm_f32, dim3(256 * 32), dim3(256), 0, stream,
                     outh, 512, Wih1, 512, xg, 2048, b1, 32, 512);
  if (chosen == 1)
    hipLaunchKernelGGL(lstm_rec_hi2, dim3(128), dim3(512), 0, stream, xg, whh1U, outh, lens);
  else
    hipLaunchKernelGGL(lstm_rec_lo, dim3(128), dim3(1024), 0, stream, xg, whh1L, outh, lens);
  // emissions (N padded to 64) + decode
  hipLaunchKernelGGL(gemm_f32, dim3(256), dim3(256), 0, stream,
                     outh, 512, Bot, 512, emis, 64, biaso, 1, 512);
  hipLaunchKernelGGL(check_nan, dim3(256), dim3(256), 0, stream,
                     emis, (long)TB_ * 64, diag);
  hipLaunchKernelGGL(viterbi, dim3(B_), dim3(64), 0, stream,
                     emis, trans, startv, endv, lens, outp);
  hipLaunchKernelGGL(verdict, dim3(1), dim3(64), 0, stream, diag, outp);
}